// Round 4
// baseline (93.057 us; speedup 1.0000x reference)
//
#include <hip/hip_runtime.h>
#include <stdint.h>

#define NB 32768   // batch
#define NN 128     // stages

typedef __attribute__((ext_vector_type(8))) short bf16x8;
typedef __attribute__((ext_vector_type(4))) float f32x4;

__device__ __forceinline__ uint16_t f2bf(float v) {
    uint32_t u = __float_as_uint(v);
    u += 0x7FFF + ((u >> 16) & 1);   // RNE
    return (uint16_t)(u >> 16);
}

// Wc layout (in d_ws), all bf16, XOR-swizzled in 64-elem halves:
//   u16[0      .. 32768) : B1 [256 c][128 k]   = Wx, swz key (c&7)
//   u16[32768  .. 65536) : B2 [512 row][64 kk] : rows 0..255 = S1 (Wy[mk][kk]),
//                          rows 256..511 = S2 (Wy[mk][65+kk]), swz key (row&7)
__global__ void puf_prep(const float* __restrict__ Wx, const float* __restrict__ Wy,
                         uint16_t* __restrict__ Wc) {
    int idx = blockIdx.x * 256 + threadIdx.x;   // 65536 total
    if (idx < 32768) {
        int c = idx >> 7, k = idx & 127;
        float v = Wx[c * NN + k];
        Wc[c * 128 + ((k & 64) | ((k & 63) ^ ((c & 7) << 3)))] = f2bf(v);
    } else {
        int j = idx - 32768;
        int row = j >> 6, kk = j & 63;
        int mk = row & 255;
        float v = (row < 256) ? Wy[mk * 130 + kk] : Wy[mk * 130 + 65 + kk];
        Wc[32768 + row * 64 + (kk ^ ((row & 7) << 3))] = f2bf(v);
    }
}

// 512 blocks x 512 threads: block = 128 batch rows x one m-half (16 of 32 m's).
// Blocks t and t+256 share the same x rows (same XCD via round-robin: 256%8==0).
__global__ __launch_bounds__(512, 4) void puf_main(
    const float* __restrict__ x, const float* __restrict__ bx,
    const float* __restrict__ Wy, const uint16_t* __restrict__ Wc,
    float* __restrict__ out)
{
    __shared__ __align__(16) uint16_t As[128 * 128];  // 32 KB phi tile (swizzled ±1)
    __shared__ __align__(16) uint16_t Bs[128 * 128];  // 32 KB: B1 [128][128] then B2 [256][64]
    __shared__ float Xo[128 * 17];                    // 8.5 KB x_out[row][m_local], pad 17
    __shared__ float Sg[128];                         // phi[r][64]

    const int tid = threadIdx.x;
    const int w = tid >> 6, l = tid & 63;
    const int wr = w >> 2, wc = w & 3;     // wave: 64 rows x 32 cols
    const int l15 = l & 15, l4 = l >> 4;
    const int bid = blockIdx.x;
    const int h = bid >> 8;                // m-half: 0 or 1
    const int row0 = (bid & 255) * 128;

    // --- early VMEM: scattered per-col constants, B1 stage, x rows (in order) ---
    float bxv[2], epsv[2], pivv[2];
#pragma unroll
    for (int cf = 0; cf < 2; ++cf) {
        int c = h * 128 + wc * 32 + cf * 16 + l15;
        bxv[cf]  = bx[c];
        pivv[cf] = Wy[c * 130 + 64];
        epsv[cf] = Wy[c * 130 + 129];
    }
    const uint4* wcu4 = (const uint4*)Wc;
    uint4 s1[4];
#pragma unroll
    for (int it = 0; it < 4; ++it) s1[it] = wcu4[h * 2048 + it * 512 + tid];

    float xa[16], xb[16];
#pragma unroll
    for (int i = 0; i < 16; ++i) {
        int grow = row0 + w * 16 + i;
        xa[i] = x[grow * NN + l];
        xb[i] = x[grow * NN + 64 + l];
    }

    // B1 weights -> LDS (linear copy; swizzle pre-baked in Wc)
#pragma unroll
    for (int it = 0; it < 4; ++it) ((uint4*)Bs)[it * 512 + tid] = s1[it];

    // phi via ballot parity -> As (swizzled ±1 bf16)
#pragma unroll
    for (int i = 0; i < 16; ++i) {
        int r = w * 16 + i;
        unsigned long long m0 = __ballot(xa[i] > 0.5f);  // x[r][0..63]
        unsigned long long m1 = __ballot(xb[i] > 0.5f);  // x[r][64..127]
        int onesHi = __popcll(m1);
        int parLo = (__popcll(m0 >> l) + onesHi) & 1;    // parity x[r][l..127]
        int parHi = (__popcll(m1 >> l)) & 1;             // parity x[r][64+l..127]
        int sw = (r & 7) << 3;
        As[r * 128 + (l ^ sw)]        = parLo ? 0xBF80u : 0x3F80u;
        As[r * 128 + (64 + (l ^ sw))] = parHi ? 0xBF80u : 0x3F80u;
        if (l == 0) Sg[r] = (onesHi & 1) ? -1.0f : 1.0f; // phi[r][64]
    }
    __syncthreads();

    // issue B2 stage loads now; HBM/L2 latency hides under B1 GEMM
    uint4 s2[4];
#pragma unroll
    for (int it = 0; it < 4; ++it) {
        int idx = it * 512 + tid;                        // [0,2048)
        int src = (idx < 1024) ? (4096 + h * 1024 + idx) // S1 chunk
                               : (5120 + h * 1024 + idx);// S2 chunk
        s2[it] = wcu4[src];
    }

    // ---------------- B1 GEMM: 128 rows x 128 cols, K=128 ----------------
    const f32x4 zero4 = {0.0f, 0.0f, 0.0f, 0.0f};
    f32x4 acc1[4][2];
#pragma unroll
    for (int a = 0; a < 4; ++a)
#pragma unroll
        for (int b = 0; b < 2; ++b) acc1[a][b] = zero4;

    __builtin_amdgcn_s_setprio(1);
#pragma unroll
    for (int t = 0; t < 4; ++t) {
        int k = t * 32 + l4 * 8;
        bf16x8 af[4], bf[2];
#pragma unroll
        for (int rf = 0; rf < 4; ++rf) {
            int r = wr * 64 + rf * 16 + l15;
            af[rf] = *(const bf16x8*)&As[r * 128 + ((k & 64) | ((k & 63) ^ ((r & 7) << 3)))];
        }
#pragma unroll
        for (int cf = 0; cf < 2; ++cf) {
            int cl = wc * 32 + cf * 16 + l15;
            bf[cf] = *(const bf16x8*)&Bs[cl * 128 + ((k & 64) | ((k & 63) ^ ((cl & 7) << 3)))];
        }
#pragma unroll
        for (int rf = 0; rf < 4; ++rf)
#pragma unroll
            for (int cf = 0; cf < 2; ++cf)
                acc1[rf][cf] = __builtin_amdgcn_mfma_f32_16x16x32_bf16(af[rf], bf[cf], acc1[rf][cf], 0, 0, 0);
    }
    __builtin_amdgcn_s_setprio(0);
    __syncthreads();  // done reading Bs (B1 view)

    // write staged B2 weights (Bs reused as [256][64]: rows 0..127 S1, 128..255 S2)
#pragma unroll
    for (int it = 0; it < 4; ++it) ((uint4*)Bs)[it * 512 + tid] = s2[it];

    // ---------------- B1 epilogue: x_out -> Xo ----------------
#pragma unroll
    for (int rf = 0; rf < 4; ++rf) {
#pragma unroll
        for (int cf = 0; cf < 2; ++cf) {
            float p[4];
#pragma unroll
            for (int q = 0; q < 4; ++q) p[q] = acc1[rf][cf][q] + bxv[cf];
#pragma unroll
            for (int q = 0; q < 4; ++q) {
                p[q] *= __shfl_xor(p[q], 1);
                p[q] *= __shfl_xor(p[q], 2);
                p[q] *= __shfl_xor(p[q], 4);
            }
            if ((l & 7) == 0) {
                int m = wc * 4 + cf * 2 + (l15 >> 3);
#pragma unroll
                for (int q = 0; q < 4; ++q) {
                    int r = wr * 64 + rf * 16 + l4 * 4 + q;
                    float sig = 1.0f / (1.0f + __expf(-p[q]));
                    Xo[r * 17 + m] = 1.0f - 2.0f * sig;
                }
            }
        }
    }
    __syncthreads();  // B2 weights + Xo ready

    // ---------------- B2 GEMMs: S1 (k<64) and S2 (k>=64) ----------------
    f32x4 accS1[4][2], accS2[4][2];
#pragma unroll
    for (int a = 0; a < 4; ++a)
#pragma unroll
        for (int b = 0; b < 2; ++b) { accS1[a][b] = zero4; accS2[a][b] = zero4; }

    __builtin_amdgcn_s_setprio(1);
#pragma unroll
    for (int t = 0; t < 2; ++t) {
        int kk = t * 32 + l4 * 8;
        bf16x8 af1[4], af2[4], b1[2], b2[2];
#pragma unroll
        for (int rf = 0; rf < 4; ++rf) {
            int r = wr * 64 + rf * 16 + l15;
            int swr = (r & 7) << 3;
            af1[rf] = *(const bf16x8*)&As[r * 128 + (kk ^ swr)];
            af2[rf] = *(const bf16x8*)&As[r * 128 + (64 | (kk ^ swr))];
        }
#pragma unroll
        for (int cf = 0; cf < 2; ++cf) {
            int cl = wc * 32 + cf * 16 + l15;
            int swc = (cl & 7) << 3;
            b1[cf] = *(const bf16x8*)&Bs[cl * 64 + (kk ^ swc)];
            b2[cf] = *(const bf16x8*)&Bs[(128 + cl) * 64 + (kk ^ swc)];
        }
#pragma unroll
        for (int rf = 0; rf < 4; ++rf)
#pragma unroll
            for (int cf = 0; cf < 2; ++cf) {
                accS1[rf][cf] = __builtin_amdgcn_mfma_f32_16x16x32_bf16(af1[rf], b1[cf], accS1[rf][cf], 0, 0, 0);
                accS2[rf][cf] = __builtin_amdgcn_mfma_f32_16x16x32_bf16(af2[rf], b2[cf], accS2[rf][cf], 0, 0, 0);
            }
    }
    __builtin_amdgcn_s_setprio(0);

    // ---------------- B2 epilogue: combine, product over ky, sigmoid, store ----------------
#pragma unroll
    for (int rf = 0; rf < 4; ++rf) {
#pragma unroll
        for (int cf = 0; cf < 2; ++cf) {
            int m = wc * 4 + cf * 2 + (l15 >> 3);
            float p[4];
#pragma unroll
            for (int q = 0; q < 4; ++q) {
                int r = wr * 64 + rf * 16 + l4 * 4 + q;
                float xo  = Xo[r * 17 + m];
                float axo = fabsf(xo);
                float sv1 = accS1[rf][cf][q] + Sg[r] * pivv[cf];
                float sv2 = accS2[rf][cf][q] + epsv[cf];
                p[q] = xo * sv1 + axo * sv2;
            }
#pragma unroll
            for (int q = 0; q < 4; ++q) {
                p[q] *= __shfl_xor(p[q], 1);
                p[q] *= __shfl_xor(p[q], 2);
                p[q] *= __shfl_xor(p[q], 4);
            }
            if ((l & 7) == 0) {
                f32x4 o;
#pragma unroll
                for (int q = 0; q < 4; ++q) o[q] = 1.0f / (1.0f + __expf(-p[q]));
                int rbase = row0 + wr * 64 + rf * 16 + l4 * 4;
                *(f32x4*)&out[(h * 16 + m) * NB + rbase] = o;
            }
        }
    }
}

extern "C" void kernel_launch(void* const* d_in, const int* in_sizes, int n_in,
                              void* d_out, int out_size, void* d_ws, size_t ws_size,
                              hipStream_t stream) {
    const float* x  = (const float*)d_in[0];
    const float* Wx = (const float*)d_in[1];
    const float* bx = (const float*)d_in[2];
    const float* Wy = (const float*)d_in[3];
    float* out = (float*)d_out;
    uint16_t* Wc = (uint16_t*)d_ws;   // 128 KB used

    puf_prep<<<dim3(256), dim3(256), 0, stream>>>(Wx, Wy, Wc);
    puf_main<<<dim3(512), dim3(512), 0, stream>>>(x, bx, Wy, Wc, out);
}